// Round 18
// baseline (237.883 us; speedup 1.0000x reference)
//
#include <hip/hip_runtime.h>

typedef unsigned short u16;
typedef unsigned int   u32;
typedef unsigned long long u64;
typedef __attribute__((ext_vector_type(4))) float f4;
typedef __attribute__((ext_vector_type(8))) short s8;
typedef __attribute__((ext_vector_type(4))) int   i4v;
typedef __attribute__((ext_vector_type(4))) unsigned short u16x4;

#define DEV __device__ __forceinline__

DEV u16 f2b(float f) {
  union { __bf16 b; u16 u; } c; c.b = (__bf16)f; return c.u;
}
DEV float b2f(u16 h) { return __uint_as_float(((u32)h) << 16); }

// ---------------- workspace layout (bytes) ----------------
#define OFF_STATS 0L
#define OFF_W1B   65536L
#define OFF_WEAB  688128L
#define OFF_W2B   950272L
#define OFF_W3B   1081344L
#define OFF_IDX   1146880L
#define OFF_PQ    2457600L
#define OFF_Y1    44040192L     /* 8.4 MB bf16 */
#define OFF_Y2    4194304L      /* 16.8 MB bf16 */
#define OFF_EMAX  23068672L     /* 8.4 MB bf16 */
#define OFF_EMIN  41943040L     /* 8.4 MB bf16 */
#define OFF_Y3    4194304L      /* 8.4 MB bf16 over dead Y2 */
#define OFF_Y4    23068672L     /* 8.4 MB f32 over dead EMAX */
#define WS_NEED   71303168L

// ---------------- weight convert -> bf16 + point prep ----------------
__global__ __launch_bounds__(256) void k_convw(
    const float* __restrict__ w1, const float* __restrict__ we,
    const float* __restrict__ w2, const float* __restrict__ w3,
    const float* __restrict__ p,
    u16* __restrict__ w1b, u16* __restrict__ weABb,
    u16* __restrict__ w2b, u16* __restrict__ w3b, f4* __restrict__ pqg)
{
  int i = blockIdx.x * 256 + threadIdx.x;
  if (i < 311296) { w1b[i] = f2b(w1[i]); return; }
  i -= 311296;
  if (i < 131072) {
    int o = i >> 8, c = i & 255;
    float v = (o < 256) ? we[o * 512 + c]
                        : we[(o - 256) * 512 + 256 + c] - we[(o - 256) * 512 + c];
    weABb[i] = f2b(v); return;
  }
  i -= 131072;
  if (i < 65536) { w2b[i] = f2b(w2[i]); return; }
  i -= 65536;
  if (i < 32768) { w3b[i] = f2b(w3[i]); return; }
  i -= 32768;
  if (i < 16384) {
    int b = i >> 13, n = i & 8191;
    const float* pb = p + (long)b * 24576;
    float X = pb[n], Y = pb[8192 + n], Z = pb[16384 + n];
    f4 v; v[0] = X; v[1] = Y; v[2] = Z; v[3] = fmaf(X, X, fmaf(Y, Y, Z * Z));
    pqg[i] = v;
  }
}

DEV float lky(float z) { return z > 0.f ? z : 0.2f * z; }

#define XSTRIDE 130
DEV s8 packFragU(const float* __restrict__ sBf, int kb, int nl) {
  union { u16 u[8]; s8 v; } r;
#pragma unroll
  for (int i = 0; i < 8; ++i) r.u[i] = f2b(sBf[(kb + i) * XSTRIDE + nl]);
  return r.v;
}

// ================== FUSED: knn (1024 blocks) + gemm1 (256 blocks), interleaved 4:1 ==================
// blk%5==4 -> gemm1 tile gid=blk/5 ; else knn block kid=(blk/5)*4 + blk%5.
// LDS union: knn 24640 B | gemm 50688 B.
__global__ __launch_bounds__(256, 3) void k_knn_g1(
    const f4* __restrict__ pqg, int* __restrict__ idxOut,
    const u16* __restrict__ A, const float* __restrict__ x,
    float* __restrict__ gsums, float* __restrict__ gssq, u16* __restrict__ Y1b)
{
  __shared__ __align__(16) char U[50688];
  const int blk = blockIdx.x;
  const int tid = threadIdx.x, lane = tid & 63, w = tid >> 6;

  if ((blk % 5) == 4) {
    // gemm1 body: Y1[b][n][o] = sum_k w1[o][k]*x[b][k][n], M=256, K=1216
    const int gid = blk / 5;
    const int b = gid >> 7;
    const int m0 = ((gid >> 6) & 1) * 128;
    const int n0 = (gid & 63) * 128;
    const int K = 1216, M = 256;
    u16* sA = (u16*)U;                          // [2][4096]
    float* s_sum = (float*)(U + 49664);
    float* s_ssq = (float*)(U + 50176);
    const int wr = w >> 1, wc = w & 1;
    const int r15 = lane & 15, g8 = (lane >> 4) * 8;
    if (tid < 128) { s_sum[tid] = 0.f; s_ssq[tid] = 0.f; }

    f4 acc[4][4];
#pragma unroll
    for (int i = 0; i < 4; ++i)
#pragma unroll
      for (int j = 0; j < 4; ++j) { f4 z = {0.f, 0.f, 0.f, 0.f}; acc[i][j] = z; }

    const int row0 = tid >> 2;
    const int kp0 = (tid & 3) << 3;
    const u16* gA0 = A + (long)(m0 + row0) * K + kp0;
    const u16* gA1 = A + (long)(m0 + row0 + 64) * K + kp0;
    const int ch0 = tid, ch1 = tid + 256;
    const int kS = tid >> 3, nS = (tid & 7) << 2;
    const float* gX = x + (long)b * 1216 * 8192 + (long)kS * 8192 + n0 + nS;

    ((i4v*)sA)[ch0] = *(const i4v*)gA0;
    ((i4v*)sA)[ch1] = *(const i4v*)gA1;
    {
      float* sBf0 = (float*)(U + 16384);
#pragma unroll
      for (int it = 0; it < 4; ++it) {
        f4 v = *(const f4*)(gX + it * 32);
        float* dst = sBf0 + kS * XSTRIDE + nS + it * 32;
        ((float2*)dst)[0] = make_float2(v[0], v[1]);
        ((float2*)dst)[1] = make_float2(v[2], v[3]);
      }
    }
    __syncthreads();

    const int KT = K >> 5;   // 38
    int cur = 0;
    for (int kk = 0; kk < KT; ++kk) {
      const bool more = (kk + 1 < KT);
      i4v ra0, ra1;
      f4 xv[4];
      if (more) {
        long ko = (long)(kk + 1) * 32;
        ra0 = *(const i4v*)(gA0 + ko); ra1 = *(const i4v*)(gA1 + ko);
        const float* gx = gX + ko * 8192;
#pragma unroll
        for (int it = 0; it < 4; ++it) xv[it] = *(const f4*)(gx + it * 32);
      }
      const u16* la = sA + cur * 4096;
      const float* sBfc = (const float*)(U + 16384 + cur * 16640);
      s8 af[4], bfr[4];
#pragma unroll
      for (int mi = 0; mi < 4; ++mi)
        af[mi] = *(const s8*)(la + (wr * 64 + mi * 16 + r15) * 32 + g8);
#pragma unroll
      for (int ni = 0; ni < 4; ++ni)
        bfr[ni] = packFragU(sBfc, g8, wc * 64 + ni * 16 + r15);
#pragma unroll
      for (int mi = 0; mi < 4; ++mi)
#pragma unroll
        for (int ni = 0; ni < 4; ++ni)
          acc[mi][ni] = __builtin_amdgcn_mfma_f32_16x16x32_bf16(af[mi], bfr[ni], acc[mi][ni], 0, 0, 0);
      if (more) {
        u16* na = sA + (cur ^ 1) * 4096;
        ((i4v*)na)[ch0] = ra0;
        ((i4v*)na)[ch1] = ra1;
        float* sBfn = (float*)(U + 16384 + (cur ^ 1) * 16640);
#pragma unroll
        for (int it = 0; it < 4; ++it) {
          float* dst = sBfn + kS * XSTRIDE + nS + it * 32;
          ((float2*)dst)[0] = make_float2(xv[it][0], xv[it][1]);
          ((float2*)dst)[1] = make_float2(xv[it][2], xv[it][3]);
        }
      }
      __syncthreads();
      cur ^= 1;
    }
    const int og = m0 + wr * 64 + (lane >> 4) * 4;
    const int ng = n0 + wc * 64 + r15;
    u16* Yp = Y1b + (long)b * 8192 * 256;
#pragma unroll
    for (int mi = 0; mi < 4; ++mi)
#pragma unroll
      for (int ni = 0; ni < 4; ++ni) {
        f4 a = acc[mi][ni];
        u16x4 r;
#pragma unroll
        for (int q = 0; q < 4; ++q) r[q] = f2b(a[q]);
        *(u16x4*)(Yp + (long)(ng + ni * 16) * M + og + mi * 16) = r;
      }
#pragma unroll
    for (int mi = 0; mi < 4; ++mi)
#pragma unroll
      for (int j = 0; j < 4; ++j) {
        float s = 0.f, q = 0.f;
#pragma unroll
        for (int ni = 0; ni < 4; ++ni) {
          float v = acc[mi][ni][j];
          s += v; q = fmaf(v, v, q);
        }
#pragma unroll
        for (int off = 1; off < 16; off <<= 1) {
          s += __shfl_xor(s, off);
          q += __shfl_xor(q, off);
        }
        if ((lane & 15) == 0) {
          int lc = wr * 64 + (lane >> 4) * 4 + mi * 16 + j;
          atomicAdd(&s_sum[lc], s);
          atomicAdd(&s_ssq[lc], q);
        }
      }
    __syncthreads();
    if (tid < 128) {
      atomicAdd(&gsums[m0 + tid], s_sum[tid]);
      atomicAdd(&gssq[m0 + tid], s_ssq[tid]);
    }
    return;
  }

  // knn body
  const int kid = (blk / 5) * 4 + (blk % 5);
  f4* chunk = (f4*)U;                                   // [1024] 16 KB
  u16 (*cand)[4][128] = (u16(*)[4][128])(U + 16384);    // 4 KB
  double (*ckeyv)[128] = (double(*)[128])(U + 20480);   // 4 KB
  int (*scnt)[4] = (int(*)[4])(U + 24576);              // 64 B
  const int b = kid >> 9;
  const int qbase = ((kid & 511) << 4) + (w << 2);
  const f4* __restrict__ P = pqg + ((long)b << 13);
  if (lane < 4) scnt[w][lane] = 0;
  float qx2[4], qy2[4], qz2[4];
#pragma unroll
  for (int j = 0; j < 4; ++j) {
    f4 Q = P[qbase + j];
    qx2[j] = Q[0] + Q[0]; qy2[j] = Q[1] + Q[1]; qz2[j] = Q[2] + Q[2];
  }
  float mx[4];
#pragma unroll
  for (int j = 0; j < 4; ++j) mx[j] = -3.0e38f;
  for (int c = 0; c < 8; ++c) {
    __syncthreads();
#pragma unroll
    for (int i = 0; i < 4; ++i) chunk[tid + i * 256] = P[c * 1024 + tid + i * 256];
    __syncthreads();
#pragma unroll 2
    for (int t = 0; t < 16; ++t) {
      f4 cc = chunk[(t << 6) + lane];
#pragma unroll
      for (int j = 0; j < 4; ++j) {
        float v = fmaf(qx2[j], cc[0], fmaf(qy2[j], cc[1], fmaf(qz2[j], cc[2], -cc[3])));
        mx[j] = fmaxf(mx[j], v);
      }
    }
  }
  float sv[4];
#pragma unroll
  for (int j = 0; j < 4; ++j) sv[j] = mx[j];
#pragma unroll
  for (int k = 2; k <= 64; k <<= 1) {
#pragma unroll
    for (int s = k >> 1; s > 0; s >>= 1) {
      const bool takeMin = (((lane & k) == 0) == ((lane & s) == 0));
#pragma unroll
      for (int j = 0; j < 4; ++j) {
        float o = __shfl_xor(sv[j], s);
        sv[j] = takeMin ? fminf(sv[j], o) : fmaxf(sv[j], o);
      }
    }
  }
  float T[4];
#pragma unroll
  for (int j = 0; j < 4; ++j) T[j] = __shfl(sv[j], 44) - 1e-3f;
  for (int c = 0; c < 8; ++c) {
    __syncthreads();
#pragma unroll
    for (int i = 0; i < 4; ++i) chunk[tid + i * 256] = P[c * 1024 + tid + i * 256];
    __syncthreads();
#pragma unroll 2
    for (int t = 0; t < 16; ++t) {
      f4 cc = chunk[(t << 6) + lane];
#pragma unroll
      for (int j = 0; j < 4; ++j) {
        float v = fmaf(qx2[j], cc[0], fmaf(qy2[j], cc[1], fmaf(qz2[j], cc[2], -cc[3])));
        if (v >= T[j]) {
          int pos = atomicAdd(&scnt[w][j], 1);
          if (pos < 128) cand[w][j][pos] = (u16)(c * 1024 + (t << 6) + lane);
        }
      }
    }
  }
  asm volatile("s_waitcnt lgkmcnt(0)" ::: "memory");
  for (int j = 0; j < 4; ++j) {
    int cn = scnt[w][j]; if (cn > 128) cn = 128;
    f4 Q = P[qbase + j];
    const double Qx = (double)Q[0], Qy = (double)Q[1], Qz = (double)Q[2];
    const double Qs = Qx * Qx + Qy * Qy + Qz * Qz;
    double myV[2]; int myI[2];
#pragma unroll
    for (int jj = 0; jj < 2; ++jj) {
      const int e = lane + (jj << 6);
      myV[jj] = -1.0e300; myI[jj] = 0x7FFFFFFF;
      if (e < cn) {
        const int ci = cand[w][j][e];
        f4 c = P[ci];
        double cx = (double)c[0], cy = (double)c[1], cz = (double)c[2];
        double v = 2.0 * (Qx * cx + Qy * cy + Qz * cz) - Qs - (cx * cx + cy * cy + cz * cz);
        myV[jj] = v; myI[jj] = ci;
        ckeyv[w][e] = v;
      }
    }
    asm volatile("s_waitcnt lgkmcnt(0)" ::: "memory");
    int rk0 = 0, rk1 = 0;
#pragma unroll 4
    for (int e2 = 0; e2 < cn; ++e2) {
      double ov = ckeyv[w][e2];
      int oi = (int)cand[w][j][e2];
      rk0 += ((ov > myV[0]) || (ov == myV[0] && oi < myI[0])) ? 1 : 0;
      rk1 += ((ov > myV[1]) || (ov == myV[1] && oi < myI[1])) ? 1 : 0;
    }
    int* orow = idxOut + (((long)b << 13) + qbase + j) * 20;
    if (lane < cn && rk0 < 20) orow[rk0] = myI[0];
    if (lane + 64 < cn && rk1 < 20) orow[rk1] = myI[1];
    asm volatile("s_waitcnt lgkmcnt(0)" ::: "memory");
  }
}

// ---------------- fused apply helpers ----------------
DEV i4v applyPack8(i4v raw, const float* sc, const float* sh, int kb) {
  u16 r[8];
#pragma unroll
  for (int e = 0; e < 8; ++e) {
    u32 dw = (u32)raw[e >> 1];
    u16 h = (e & 1) ? (u16)(dw >> 16) : (u16)(dw & 0xFFFFu);
    r[e] = f2b(lky(fmaf(sc[kb + e], b2f(h), sh[kb + e])));
  }
  i4v o;
#pragma unroll
  for (int e = 0; e < 4; ++e) o[e] = (int)((u32)r[2 * e] | ((u32)r[2 * e + 1] << 16));
  return o;
}

DEV i4v selPack8b(i4v rawM, i4v rawN, const float* sc, const float* sh, int kb) {
  u16 r[8];
#pragma unroll
  for (int e = 0; e < 8; ++e) {
    u32 dM = (u32)rawM[e >> 1], dN = (u32)rawN[e >> 1];
    u16 hM = (e & 1) ? (u16)(dM >> 16) : (u16)(dM & 0xFFFFu);
    u16 hN = (e & 1) ? (u16)(dN >> 16) : (u16)(dN & 0xFFFFu);
    float s = sc[kb + e];
    float y = (s >= 0.f) ? b2f(hM) : b2f(hN);
    r[e] = f2b(lky(fmaf(s, y, sh[kb + e])));
  }
  i4v o;
#pragma unroll
  for (int e = 0; e < 4; ++e) o[e] = (int)((u32)r[2 * e] | ((u32)r[2 * e + 1] << 16));
  return o;
}

// ---------------- bf16 MFMA GEMM (modes 1,2) ----------------
template<int BMODE, int STATS, int BF16OUT>
__global__ __launch_bounds__(256, 2) void k_gemm(
    const u16* __restrict__ A, const void* __restrict__ B0v, const void* __restrict__ B1v,
    const float* __restrict__ sums, const float* __restrict__ ssq,
    const float* __restrict__ g, const float* __restrict__ bt, float invCount,
    float* __restrict__ gsums, float* __restrict__ gssq,
    void* __restrict__ Yv, int M, int K, long strideB, long strideY)
{
  __shared__ u16 sA[2][4096];
  __shared__ __align__(16) u16 sB[2][4096];
  __shared__ float scB[256], shB[256];
  __shared__ float s_sum[128], s_ssq[128];
  const int b = blockIdx.z;
  const int m0 = blockIdx.y * 128;
  const int n0 = blockIdx.x * 128;
  const int tid = threadIdx.x, lane = tid & 63, w = tid >> 6;
  const int wr = w >> 1, wc = w & 1;
  const int r15 = lane & 15, g8 = (lane >> 4) * 8;

  {
    float m = sums[tid] * invCount;
    float v = ssq[tid] * invCount - m * m;
    float s = g[tid] / sqrtf(v + 1e-5f);
    scB[tid] = s;
    shB[tid] = bt[tid] - m * s;
  }
  if (STATS) { if (tid < 128) { s_sum[tid] = 0.f; s_ssq[tid] = 0.f; } }
  __syncthreads();

  f4 acc[4][4];
#pragma unroll
  for (int i = 0; i < 4; ++i)
#pragma unroll
    for (int j = 0; j < 4; ++j) { f4 z = {0.f, 0.f, 0.f, 0.f}; acc[i][j] = z; }

  const int row0 = tid >> 2;
  const int kp0 = (tid & 3) << 3;
  const u16* gA0 = A + (long)(m0 + row0) * K + kp0;
  const u16* gA1 = A + (long)(m0 + row0 + 64) * K + kp0;
  const int ch0 = tid, ch1 = tid + 256;

  const u16* gB0 = (const u16*)B0v + (long)b * strideB + (long)(n0 + row0) * K + kp0;
  const u16* gB1 = gB0 + (long)64 * K;
  const u16* nB0 = (const u16*)B1v + (long)b * strideB + (long)(n0 + row0) * K + kp0;
  const u16* nB1 = nB0 + (long)64 * K;

  if (BMODE == 1) {
    ((i4v*)sB[0])[ch0] = applyPack8(*(const i4v*)gB0, scB, shB, kp0);
    ((i4v*)sB[0])[ch1] = applyPack8(*(const i4v*)gB1, scB, shB, kp0);
  } else {
    ((i4v*)sB[0])[ch0] = selPack8b(*(const i4v*)gB0, *(const i4v*)nB0, scB, shB, kp0);
    ((i4v*)sB[0])[ch1] = selPack8b(*(const i4v*)gB1, *(const i4v*)nB1, scB, shB, kp0);
  }
  ((i4v*)sA[0])[ch0] = *(const i4v*)gA0;
  ((i4v*)sA[0])[ch1] = *(const i4v*)gA1;
  __syncthreads();

  const int KT = K >> 5;
  int cur = 0;
  for (int kk = 0; kk < KT; ++kk) {
    const bool more = (kk + 1 < KT);
    i4v ra0, ra1, rb0, rb1, rn0, rn1;
    if (more) {
      long ko = (long)(kk + 1) * 32;
      ra0 = *(const i4v*)(gA0 + ko); ra1 = *(const i4v*)(gA1 + ko);
      rb0 = *(const i4v*)(gB0 + ko); rb1 = *(const i4v*)(gB1 + ko);
      if (BMODE == 2) { rn0 = *(const i4v*)(nB0 + ko); rn1 = *(const i4v*)(nB1 + ko); }
    }
    const u16* la = sA[cur];
    const u16* lb = sB[cur];
    s8 af[4], bfr[4];
#pragma unroll
    for (int mi = 0; mi < 4; ++mi)
      af[mi] = *(const s8*)(la + (wr * 64 + mi * 16 + r15) * 32 + g8);
#pragma unroll
    for (int ni = 0; ni < 4; ++ni)
      bfr[ni] = *(const s8*)(lb + (wc * 64 + ni * 16 + r15) * 32 + g8);
#pragma unroll
    for (int mi = 0; mi < 4; ++mi)
#pragma unroll
      for (int ni = 0; ni < 4; ++ni)
        acc[mi][ni] = __builtin_amdgcn_mfma_f32_16x16x32_bf16(af[mi], bfr[ni], acc[mi][ni], 0, 0, 0);
    if (more) {
      ((i4v*)sA[cur ^ 1])[ch0] = ra0; ((i4v*)sA[cur ^ 1])[ch1] = ra1;
      const int kb = (kk + 1) * 32 + kp0;
      if (BMODE == 1) {
        ((i4v*)sB[cur ^ 1])[ch0] = applyPack8(rb0, scB, shB, kb);
        ((i4v*)sB[cur ^ 1])[ch1] = applyPack8(rb1, scB, shB, kb);
      } else {
        ((i4v*)sB[cur ^ 1])[ch0] = selPack8b(rb0, rn0, scB, shB, kb);
        ((i4v*)sB[cur ^ 1])[ch1] = selPack8b(rb1, rn1, scB, shB, kb);
      }
    }
    __syncthreads();
    cur ^= 1;
  }
  const int og = m0 + wr * 64 + (lane >> 4) * 4;
  const int ng = n0 + wc * 64 + r15;
  if (BF16OUT) {
    u16* Yp = (u16*)Yv + (long)b * strideY;
#pragma unroll
    for (int mi = 0; mi < 4; ++mi)
#pragma unroll
      for (int ni = 0; ni < 4; ++ni) {
        f4 a = acc[mi][ni];
        u16x4 r;
#pragma unroll
        for (int q = 0; q < 4; ++q) r[q] = f2b(a[q]);
        *(u16x4*)(Yp + (long)(ng + ni * 16) * M + og + mi * 16) = r;
      }
  } else {
    float* Yp = (float*)Yv + (long)b * strideY;
#pragma unroll
    for (int mi = 0; mi < 4; ++mi)
#pragma unroll
      for (int ni = 0; ni < 4; ++ni)
        *(f4*)(Yp + (long)(ng + ni * 16) * M + og + mi * 16) = acc[mi][ni];
  }
  if (STATS) {
#pragma unroll
    for (int mi = 0; mi < 4; ++mi)
#pragma unroll
      for (int j = 0; j < 4; ++j) {
        float s = 0.f, q = 0.f;
#pragma unroll
        for (int ni = 0; ni < 4; ++ni) {
          float v = acc[mi][ni][j];
          s += v; q = fmaf(v, v, q);
        }
#pragma unroll
        for (int off = 1; off < 16; off <<= 1) {
          s += __shfl_xor(s, off);
          q += __shfl_xor(q, off);
        }
        if ((lane & 15) == 0) {
          int lc = wr * 64 + (lane >> 4) * 4 + mi * 16 + j;
          atomicAdd(&s_sum[lc], s);
          atomicAdd(&s_ssq[lc], q);
        }
      }
    __syncthreads();
    if (tid < 128) {
      atomicAdd(&gsums[m0 + tid], s_sum[tid]);
      atomicAdd(&gssq[m0 + tid], s_ssq[tid]);
    }
  }
}

// ---------------- edgeconv gather, channel-split for L2 residency ----------------
__global__ __launch_bounds__(256, 2) void k_edge_gather(
    const u16* __restrict__ Y2, const int* __restrict__ idx,
    u16* __restrict__ Emax, u16* __restrict__ Emin,
    float* __restrict__ sums, float* __restrict__ ssq)
{
  __shared__ float s_sum[256], s_ssq[256];
  const int tid = threadIdx.x, lane = tid & 63, w = tid >> 6;
  s_sum[tid] = 0.f; s_ssq[tid] = 0.f;
  __syncthreads();
  const int half = blockIdx.y, b = blockIdx.z;
  const int ptBase = blockIdx.x * 64 + w * 16;
  const int sub = lane >> 5;
  const int chOff = half * 128 + ((lane & 31) << 2);
  f4 lsum = {0.f, 0.f, 0.f, 0.f}, lssq = {0.f, 0.f, 0.f, 0.f};
  for (int i = 0; i < 8; ++i) {
    const int pt = ptBase + i * 2 + sub;
    const long gp = (long)b * 8192 + pt;
    u16x4 cr = *(const u16x4*)(Y2 + gp * 512 + 256 + chOff);
    f4 ctr; ctr[0] = b2f(cr[0]); ctr[1] = b2f(cr[1]); ctr[2] = b2f(cr[2]); ctr[3] = b2f(cr[3]);
    const int* irow = idx + gp * 20;
    f4 vmax = {-3.0e38f, -3.0e38f, -3.0e38f, -3.0e38f};
    f4 vmin = {3.0e38f, 3.0e38f, 3.0e38f, 3.0e38f};
#pragma unroll 4
    for (int k = 0; k < 20; ++k) {
      int m = irow[k];
      u16x4 nr = *(const u16x4*)(Y2 + ((long)b * 8192 + m) * 512 + chOff);
#pragma unroll
      for (int j = 0; j < 4; ++j) {
        float y = b2f(nr[j]) + ctr[j];
        vmax[j] = fmaxf(vmax[j], y);
        vmin[j] = fminf(vmin[j], y);
        lsum[j] += y;
        lssq[j] = fmaf(y, y, lssq[j]);
      }
    }
    u16x4 eM, eN;
#pragma unroll
    for (int j = 0; j < 4; ++j) { eM[j] = f2b(vmax[j]); eN[j] = f2b(vmin[j]); }
    *(u16x4*)(Emax + gp * 256 + chOff) = eM;
    *(u16x4*)(Emin + gp * 256 + chOff) = eN;
  }
#pragma unroll
  for (int j = 0; j < 4; ++j) {
    atomicAdd(&s_sum[chOff + j], lsum[j]);
    atomicAdd(&s_ssq[chOff + j], lssq[j]);
  }
  __syncthreads();
  atomicAdd(&sums[tid], s_sum[tid]);
  atomicAdd(&ssq[tid], s_ssq[tid]);
}

// ---------------- final: apply(norm3+leaky) + 50x128 proj + bias; Y4 read ONCE ----------------
__global__ __launch_bounds__(64) void k_final(
    const float* __restrict__ Y4, const float* __restrict__ sums, const float* __restrict__ ssq,
    const float* __restrict__ g, const float* __restrict__ bt,
    const float* __restrict__ wf, const float* __restrict__ bf,
    float* __restrict__ out)
{
  __shared__ float swf[128][56];
  __shared__ float sc[128], sh[128], sb[52];
  const int lane = threadIdx.x;
  if (lane < 50) {
    const float* wrow = wf + lane * 128;
#pragma unroll 8
    for (int ch = 0; ch < 128; ++ch) swf[ch][lane] = wrow[ch];
    sb[lane] = bf[lane];
  } else if (lane < 52) {
#pragma unroll 8
    for (int ch = 0; ch < 128; ++ch) swf[ch][lane] = 0.f;
    sb[lane] = 0.f;
  }
#pragma unroll
  for (int t = 0; t < 2; ++t) {
    int ch = lane + t * 64;
    float m = sums[ch] * (1.0f / 16384.0f);
    float v = ssq[ch] * (1.0f / 16384.0f) - m * m;
    float s = g[ch] / sqrtf(v + 1e-5f);
    sc[ch] = s;
    sh[ch] = bt[ch] - m * s;
  }
  __syncthreads();
  const int b = blockIdx.y;
  const int n = blockIdx.x * 64 + lane;
  const float* hp = Y4 + ((long)b * 8192 + n) * 128;
  f4 av[13];
#pragma unroll
  for (int i = 0; i < 13; ++i) { f4 z = {0.f, 0.f, 0.f, 0.f}; av[i] = z; }
#pragma unroll 4
  for (int c4 = 0; c4 < 32; ++c4) {
    f4 hv = *(const f4*)(hp + c4 * 4);
#pragma unroll
    for (int e = 0; e < 4; ++e) {
      const int ch = c4 * 4 + e;
      float z = lky(fmaf(sc[ch], hv[e], sh[ch]));
#pragma unroll
      for (int o4 = 0; o4 < 13; ++o4) {
        f4 wv = *(const f4*)&swf[ch][o4 * 4];
#pragma unroll
        for (int q = 0; q < 4; ++q) av[o4][q] = fmaf(z, wv[q], av[o4][q]);
      }
    }
  }
  float* ob = out + (((long)b * 50) << 13) + n;
#pragma unroll
  for (int o4 = 0; o4 < 13; ++o4)
#pragma unroll
    for (int q = 0; q < 4; ++q) {
      int o = o4 * 4 + q;
      if (o < 50) ob[(long)o << 13] = av[o4][q] + sb[o];
    }
}

// ---------------- launcher ----------------
extern "C" void kernel_launch(void* const* d_in, const int* in_sizes, int n_in,
                              void* d_out, int out_size, void* d_ws, size_t ws_size,
                              hipStream_t stream)
{
  if ((long)ws_size < WS_NEED) return;
  const float* x   = (const float*)d_in[0];
  const float* p   = (const float*)d_in[1];
  const float* w1  = (const float*)d_in[2];
  const float* g1w = (const float*)d_in[4];
  const float* bt1 = (const float*)d_in[5];
  const float* we  = (const float*)d_in[6];
  const float* gew = (const float*)d_in[8];
  const float* bte = (const float*)d_in[9];
  const float* w2  = (const float*)d_in[10];
  const float* g2w = (const float*)d_in[12];
  const float* bt2 = (const float*)d_in[13];
  const float* w3  = (const float*)d_in[14];
  const float* g3w = (const float*)d_in[16];
  const float* bt3 = (const float*)d_in[17];
  const float* wf  = (const float*)d_in[18];
  const float* bfi = (const float*)d_in[19];

  char* ws = (char*)d_ws;
  u16* w1b   = (u16*)(ws + OFF_W1B);
  u16* weABb = (u16*)(ws + OFF_WEAB);
  u16* w2b   = (u16*)(ws + OFF_W2B);
  u16* w3b   = (u16*)(ws + OFF_W3B);
  int* idxb  = (int*)(ws + OFF_IDX);
  f4*  pqg   = (f4*)(ws + OFF_PQ);
  u16*   Y1b  = (u16*)(ws + OFF_Y1);
  u16*   Y2b  = (u16*)(ws + OFF_Y2);
  u16*   EMAX = (u16*)(ws + OFF_EMAX);
  u16*   EMIN = (u16*)(ws + OFF_EMIN);
  u16*   Y3b  = (u16*)(ws + OFF_Y3);
  float* Y4   = (float*)(ws + OFF_Y4);
  float* st0 = (float*)(ws + OFF_STATS);
  float* st1 = (float*)(ws + OFF_STATS + 4096);
  float* st2 = (float*)(ws + OFF_STATS + 8192);
  float* st3 = (float*)(ws + OFF_STATS + 12288);

  hipMemsetAsync(ws + OFF_STATS, 0, 16384, stream);
  k_convw<<<2176, 256, 0, stream>>>(w1, we, w2, w3, p, w1b, weABb, w2b, w3b, pqg);

  // fused: knn (1024 blocks) + gemm1 (256 blocks), interleaved 4:1
  k_knn_g1<<<1280, 256, 0, stream>>>(pqg, idxb, w1b, x, st0, st0 + 256, Y1b);

  // edge GEMM: B = apply1(Y1 bf16) fused -> Y2 bf16 [Anb | Cy]
  k_gemm<1, 0, 1><<<dim3(64, 4, 2), 256, 0, stream>>>(
      weABb, Y1b, nullptr, st0, st0 + 256, g1w, bt1, 1.0f / 16384.0f,
      nullptr, nullptr, Y2b, 512, 256, (long)8192 * 256, (long)8192 * 512);

  // gather: channel-split, bf16 E out, stats st1
  k_edge_gather<<<dim3(128, 2, 2), 256, 0, stream>>>(Y2b, idxb, EMAX, EMIN, st1, st1 + 256);

  // stage 2: B = sel(EMAX,EMIN) bf16 fused -> Y3 bf16 raw + stats st2
  k_gemm<2, 1, 1><<<dim3(64, 2, 2), 256, 0, stream>>>(
      w2b, EMAX, EMIN, st1, st1 + 256, gew, bte, 1.0f / 327680.0f,
      st2, st2 + 256, Y3b, 256, 256, (long)8192 * 256, (long)8192 * 256);

  // stage 3: B = apply2(Y3 bf16) fused -> Y4 f32 + stats st3
  k_gemm<1, 1, 0><<<dim3(64, 1, 2), 256, 0, stream>>>(
      w3b, Y3b, nullptr, st2, st2 + 256, g2w, bt2, 1.0f / 16384.0f,
      st3, st3 + 256, Y4, 128, 256, (long)8192 * 256, (long)8192 * 128);

  // final: apply3 fused + projection (Y4 read once)
  k_final<<<dim3(128, 2), 64, 0, stream>>>(Y4, st3, st3 + 256, g3w, bt3, wf, bfi, (float*)d_out);
}

// Round 19
// 216.020 us; speedup vs baseline: 1.1012x; 1.1012x over previous
//
#include <hip/hip_runtime.h>

typedef unsigned short u16;
typedef unsigned int   u32;
typedef unsigned long long u64;
typedef __attribute__((ext_vector_type(4))) float f4;
typedef __attribute__((ext_vector_type(8))) short s8;
typedef __attribute__((ext_vector_type(4))) int   i4v;
typedef __attribute__((ext_vector_type(4))) unsigned short u16x4;

#define DEV __device__ __forceinline__

// native bf16 cast (HW cvt, RNE)
DEV u16 f2b(float f) {
  union { __bf16 b; u16 u; } c; c.b = (__bf16)f; return c.u;
}
DEV float b2f(u16 h) { return __uint_as_float(((u32)h) << 16); }

// ---------------- workspace layout (bytes) ----------------
#define OFF_STATS 0L
#define OFF_W1B   65536L
#define OFF_WEAB  688128L
#define OFF_W2B   950272L
#define OFF_W3B   1081344L
#define OFF_IDX   1146880L
#define OFF_PQ    2457600L      /* 256 KB: (x,y,z,|c|^2) per point */
#define OFF_Y1    44040192L     /* 8.4 MB bf16, dead after edge GEMM */
#define OFF_Y2    4194304L      /* 16.8 MB bf16, dead after gather */
#define OFF_EMAX  23068672L     /* 8.4 MB bf16, dead after GEMM2 */
#define OFF_EMIN  41943040L     /* 8.4 MB bf16 */
#define OFF_Y3    4194304L      /* 8.4 MB bf16 over dead Y2 */
#define OFF_Y4    23068672L     /* 8.4 MB f32 over dead EMAX */
#define WS_NEED   71303168L

// ---------------- weight convert -> bf16 + point prep ----------------
__global__ __launch_bounds__(256) void k_convw(
    const float* __restrict__ w1, const float* __restrict__ we,
    const float* __restrict__ w2, const float* __restrict__ w3,
    const float* __restrict__ p,
    u16* __restrict__ w1b, u16* __restrict__ weABb,
    u16* __restrict__ w2b, u16* __restrict__ w3b, f4* __restrict__ pqg)
{
  int i = blockIdx.x * 256 + threadIdx.x;
  if (i < 311296) { w1b[i] = f2b(w1[i]); return; }
  i -= 311296;
  if (i < 131072) {
    int o = i >> 8, c = i & 255;
    float v = (o < 256) ? we[o * 512 + c]
                        : we[(o - 256) * 512 + 256 + c] - we[(o - 256) * 512 + c];
    weABb[i] = f2b(v); return;
  }
  i -= 131072;
  if (i < 65536) { w2b[i] = f2b(w2[i]); return; }
  i -= 65536;
  if (i < 32768) { w3b[i] = f2b(w3[i]); return; }
  i -= 32768;
  if (i < 16384) {
    int b = i >> 13, n = i & 8191;
    const float* pb = p + (long)b * 24576;
    float X = pb[n], Y = pb[8192 + n], Z = pb[16384 + n];
    f4 v; v[0] = X; v[1] = Y; v[2] = Z; v[3] = fmaf(X, X, fmaf(Y, Y, Z * Z));
    pqg[i] = v;
  }
}

// ---------------- exact KNN top-20: 4 q/wave, chunk-LDS shared across 4 waves ----------------
__global__ __launch_bounds__(256) void k_knn(const f4* __restrict__ pqg, int* __restrict__ idxOut)
{
  __shared__ f4 chunk[1024];           // 16 KB
  __shared__ u16 cand[4][4][128];      // 4 KB
  __shared__ double ckeyv[4][128];     // 4 KB
  __shared__ int scnt[4][4];
  const int tid = threadIdx.x, lane = tid & 63, w = tid >> 6;
  const int blk = blockIdx.x;          // 1024
  const int b = blk >> 9;
  const int qbase = ((blk & 511) << 4) + (w << 2);
  const f4* __restrict__ P = pqg + ((long)b << 13);
  if (lane < 4) scnt[w][lane] = 0;
  float qx2[4], qy2[4], qz2[4];
#pragma unroll
  for (int j = 0; j < 4; ++j) {
    f4 Q = P[qbase + j];
    qx2[j] = Q[0] + Q[0]; qy2[j] = Q[1] + Q[1]; qz2[j] = Q[2] + Q[2];
  }
  float mx[4];
#pragma unroll
  for (int j = 0; j < 4; ++j) mx[j] = -3.0e38f;
  for (int c = 0; c < 8; ++c) {
    __syncthreads();
#pragma unroll
    for (int i = 0; i < 4; ++i) chunk[tid + i * 256] = P[c * 1024 + tid + i * 256];
    __syncthreads();
#pragma unroll 2
    for (int t = 0; t < 16; ++t) {
      f4 cc = chunk[(t << 6) + lane];
#pragma unroll
      for (int j = 0; j < 4; ++j) {
        float v = fmaf(qx2[j], cc[0], fmaf(qy2[j], cc[1], fmaf(qz2[j], cc[2], -cc[3])));
        mx[j] = fmaxf(mx[j], v);
      }
    }
  }
  float sv[4];
#pragma unroll
  for (int j = 0; j < 4; ++j) sv[j] = mx[j];
#pragma unroll
  for (int k = 2; k <= 64; k <<= 1) {
#pragma unroll
    for (int s = k >> 1; s > 0; s >>= 1) {
      const bool takeMin = (((lane & k) == 0) == ((lane & s) == 0));
#pragma unroll
      for (int j = 0; j < 4; ++j) {
        float o = __shfl_xor(sv[j], s);
        sv[j] = takeMin ? fminf(sv[j], o) : fmaxf(sv[j], o);
      }
    }
  }
  float T[4];
#pragma unroll
  for (int j = 0; j < 4; ++j) T[j] = __shfl(sv[j], 44) - 1e-3f;
  for (int c = 0; c < 8; ++c) {
    __syncthreads();
#pragma unroll
    for (int i = 0; i < 4; ++i) chunk[tid + i * 256] = P[c * 1024 + tid + i * 256];
    __syncthreads();
#pragma unroll 2
    for (int t = 0; t < 16; ++t) {
      f4 cc = chunk[(t << 6) + lane];
#pragma unroll
      for (int j = 0; j < 4; ++j) {
        float v = fmaf(qx2[j], cc[0], fmaf(qy2[j], cc[1], fmaf(qz2[j], cc[2], -cc[3])));
        if (v >= T[j]) {
          int pos = atomicAdd(&scnt[w][j], 1);
          if (pos < 128) cand[w][j][pos] = (u16)(c * 1024 + (t << 6) + lane);
        }
      }
    }
  }
  asm volatile("s_waitcnt lgkmcnt(0)" ::: "memory");
  for (int j = 0; j < 4; ++j) {
    int cn = scnt[w][j]; if (cn > 128) cn = 128;
    f4 Q = P[qbase + j];
    const double Qx = (double)Q[0], Qy = (double)Q[1], Qz = (double)Q[2];
    const double Qs = Qx * Qx + Qy * Qy + Qz * Qz;
    double myV[2]; int myI[2];
#pragma unroll
    for (int jj = 0; jj < 2; ++jj) {
      const int e = lane + (jj << 6);
      myV[jj] = -1.0e300; myI[jj] = 0x7FFFFFFF;
      if (e < cn) {
        const int ci = cand[w][j][e];
        f4 c = P[ci];
        double cx = (double)c[0], cy = (double)c[1], cz = (double)c[2];
        double v = 2.0 * (Qx * cx + Qy * cy + Qz * cz) - Qs - (cx * cx + cy * cy + cz * cz);
        myV[jj] = v; myI[jj] = ci;
        ckeyv[w][e] = v;
      }
    }
    asm volatile("s_waitcnt lgkmcnt(0)" ::: "memory");
    int rk0 = 0, rk1 = 0;
#pragma unroll 4
    for (int e2 = 0; e2 < cn; ++e2) {
      double ov = ckeyv[w][e2];
      int oi = (int)cand[w][j][e2];
      rk0 += ((ov > myV[0]) || (ov == myV[0] && oi < myI[0])) ? 1 : 0;
      rk1 += ((ov > myV[1]) || (ov == myV[1] && oi < myI[1])) ? 1 : 0;
    }
    int* orow = idxOut + (((long)b << 13) + qbase + j) * 20;
    if (lane < cn && rk0 < 20) orow[rk0] = myI[0];
    if (lane + 64 < cn && rk1 < 20) orow[rk1] = myI[1];
    asm volatile("s_waitcnt lgkmcnt(0)" ::: "memory");
  }
}

// ---------------- fused apply helpers ----------------
DEV float lky(float z) { return z > 0.f ? z : 0.2f * z; }

DEV i4v applyPack8(i4v raw, const float* sc, const float* sh, int kb) {
  u16 r[8];
#pragma unroll
  for (int e = 0; e < 8; ++e) {
    u32 dw = (u32)raw[e >> 1];
    u16 h = (e & 1) ? (u16)(dw >> 16) : (u16)(dw & 0xFFFFu);
    r[e] = f2b(lky(fmaf(sc[kb + e], b2f(h), sh[kb + e])));
  }
  i4v o;
#pragma unroll
  for (int e = 0; e < 4; ++e) o[e] = (int)((u32)r[2 * e] | ((u32)r[2 * e + 1] << 16));
  return o;
}

DEV i4v selPack8b(i4v rawM, i4v rawN, const float* sc, const float* sh, int kb) {
  u16 r[8];
#pragma unroll
  for (int e = 0; e < 8; ++e) {
    u32 dM = (u32)rawM[e >> 1], dN = (u32)rawN[e >> 1];
    u16 hM = (e & 1) ? (u16)(dM >> 16) : (u16)(dM & 0xFFFFu);
    u16 hN = (e & 1) ? (u16)(dN >> 16) : (u16)(dN & 0xFFFFu);
    float s = sc[kb + e];
    float y = (s >= 0.f) ? b2f(hM) : b2f(hN);
    r[e] = f2b(lky(fmaf(s, y, sh[kb + e])));
  }
  i4v o;
#pragma unroll
  for (int e = 0; e < 4; ++e) o[e] = (int)((u32)r[2 * e] | ((u32)r[2 * e + 1] << 16));
  return o;
}

// pack a B-fragment from an f32 LDS tile sBf[32][130]: k = kb..kb+7, col nl (0..127)
#define XSTRIDE 130
DEV s8 packFrag(const float* __restrict__ sBf, int kb, int nl) {
  union { u16 u[8]; s8 v; } r;
#pragma unroll
  for (int i = 0; i < 8; ++i) r.u[i] = f2b(sBf[(kb + i) * XSTRIDE + nl]);
  return r.v;
}

// ---------------- bf16 MFMA GEMM: Y[b][n][o] = sum_k A[o][k]*Bapplied[b][n][k] ----------------
// BMODE 0: B0 bf16 [n][K] pre-applied. BMODE 1: B0 bf16 raw [n][K] + norm/leaky (K==256).
// BMODE 2: B0=EMAX,B1=EMIN bf16 [n][K] + sign-select + norm/leaky (K==256).
// BMODE 3: B0 = x f32 in [k][8192] layout; transpose + bf16 in staging (GEMM1).
template<int BMODE, int STATS, int BF16OUT>
__global__ __launch_bounds__(256, 2) void k_gemm(
    const u16* __restrict__ A, const void* __restrict__ B0v, const void* __restrict__ B1v,
    const float* __restrict__ sums, const float* __restrict__ ssq,
    const float* __restrict__ g, const float* __restrict__ bt, float invCount,
    float* __restrict__ gsums, float* __restrict__ gssq,
    void* __restrict__ Yv, int M, int K, long strideB, long strideY)
{
  __shared__ u16 sA[2][4096];
  __shared__ __align__(16) char sBr[2][(BMODE == 3) ? 16640 : 8192];
  __shared__ float scB[256], shB[256];
  __shared__ float s_sum[128], s_ssq[128];
  const int b = blockIdx.z;
  const int m0 = blockIdx.y * 128;
  const int n0 = blockIdx.x * 128;
  const int tid = threadIdx.x, lane = tid & 63, w = tid >> 6;
  const int wr = w >> 1, wc = w & 1;
  const int r15 = lane & 15, g8 = (lane >> 4) * 8;

  if (BMODE == 1 || BMODE == 2) {
    float m = sums[tid] * invCount;
    float v = ssq[tid] * invCount - m * m;
    float s = g[tid] / sqrtf(v + 1e-5f);
    scB[tid] = s;
    shB[tid] = bt[tid] - m * s;
  }
  if (STATS) { if (tid < 128) { s_sum[tid] = 0.f; s_ssq[tid] = 0.f; } }
  if (BMODE == 1 || BMODE == 2) __syncthreads();

  f4 acc[4][4];
#pragma unroll
  for (int i = 0; i < 4; ++i)
#pragma unroll
    for (int j = 0; j < 4; ++j) { f4 z = {0.f, 0.f, 0.f, 0.f}; acc[i][j] = z; }

  const int row0 = tid >> 2;            // 0..63
  const int kp0 = (tid & 3) << 3;       // 0,8,16,24
  const u16* gA0 = A + (long)(m0 + row0) * K + kp0;
  const u16* gA1 = A + (long)(m0 + row0 + 64) * K + kp0;
  const int ch0 = tid, ch1 = tid + 256;

  const u16* gB0 = (const u16*)B0v + (long)b * strideB + (long)(n0 + row0) * K + kp0;
  const u16* gB1 = gB0 + (long)64 * K;
  const u16* nB0 = (const u16*)B1v + (long)b * strideB + (long)(n0 + row0) * K + kp0;
  const u16* nB1 = nB0 + (long)64 * K;
  // mode 3: thread covers k-row kS (0..31), n-quads nS, nS+32, nS+64, nS+96
  const float* xB = (const float*)B0v + (long)b * strideB;
  const int kS = tid >> 3, nS = (tid & 7) << 2;
  const float* gX = xB + (long)kS * 8192 + n0 + nS;

  // prologue: stage k-tile 0
  ((i4v*)sA[0])[ch0] = *(const i4v*)gA0;
  ((i4v*)sA[0])[ch1] = *(const i4v*)gA1;
  if (BMODE == 0) {
    ((i4v*)sBr[0])[ch0] = *(const i4v*)gB0;
    ((i4v*)sBr[0])[ch1] = *(const i4v*)gB1;
  } else if (BMODE == 1) {
    ((i4v*)sBr[0])[ch0] = applyPack8(*(const i4v*)gB0, scB, shB, kp0);
    ((i4v*)sBr[0])[ch1] = applyPack8(*(const i4v*)gB1, scB, shB, kp0);
  } else if (BMODE == 2) {
    ((i4v*)sBr[0])[ch0] = selPack8b(*(const i4v*)gB0, *(const i4v*)nB0, scB, shB, kp0);
    ((i4v*)sBr[0])[ch1] = selPack8b(*(const i4v*)gB1, *(const i4v*)nB1, scB, shB, kp0);
  } else {
    float* sBf0 = (float*)sBr[0];
#pragma unroll
    for (int it = 0; it < 4; ++it) {
      f4 v = *(const f4*)(gX + it * 32);
      float* dst = sBf0 + kS * XSTRIDE + nS + it * 32;
      ((float2*)dst)[0] = make_float2(v[0], v[1]);
      ((float2*)dst)[1] = make_float2(v[2], v[3]);
    }
  }
  __syncthreads();

  const int KT = K >> 5;
  int cur = 0;
  for (int kk = 0; kk < KT; ++kk) {
    const bool more = (kk + 1 < KT);
    i4v ra0, ra1, rb0, rb1, rn0, rn1;
    f4 xv[4];
    if (more) {
      long ko = (long)(kk + 1) * 32;
      ra0 = *(const i4v*)(gA0 + ko); ra1 = *(const i4v*)(gA1 + ko);
      if (BMODE == 0 || BMODE == 1) {
        rb0 = *(const i4v*)(gB0 + ko); rb1 = *(const i4v*)(gB1 + ko);
      } else if (BMODE == 2) {
        rb0 = *(const i4v*)(gB0 + ko); rb1 = *(const i4v*)(gB1 + ko);
        rn0 = *(const i4v*)(nB0 + ko); rn1 = *(const i4v*)(nB1 + ko);
      } else {
        const float* gx = gX + ko * 8192;
#pragma unroll
        for (int it = 0; it < 4; ++it) xv[it] = *(const f4*)(gx + it * 32);
      }
    }
    const u16* la = sA[cur];
    s8 af[4], bfr[4];
#pragma unroll
    for (int mi = 0; mi < 4; ++mi)
      af[mi] = *(const s8*)(la + (wr * 64 + mi * 16 + r15) * 32 + g8);
    if (BMODE == 3) {
      const float* sBfc = (const float*)sBr[cur];
#pragma unroll
      for (int ni = 0; ni < 4; ++ni)
        bfr[ni] = packFrag(sBfc, g8, wc * 64 + ni * 16 + r15);
    } else {
      const u16* lb = (const u16*)sBr[cur];
#pragma unroll
      for (int ni = 0; ni < 4; ++ni)
        bfr[ni] = *(const s8*)(lb + (wc * 64 + ni * 16 + r15) * 32 + g8);
    }
#pragma unroll
    for (int mi = 0; mi < 4; ++mi)
#pragma unroll
      for (int ni = 0; ni < 4; ++ni)
        acc[mi][ni] = __builtin_amdgcn_mfma_f32_16x16x32_bf16(af[mi], bfr[ni], acc[mi][ni], 0, 0, 0);
    if (more) {
      ((i4v*)sA[cur ^ 1])[ch0] = ra0; ((i4v*)sA[cur ^ 1])[ch1] = ra1;
      if (BMODE == 0) {
        ((i4v*)sBr[cur ^ 1])[ch0] = rb0; ((i4v*)sBr[cur ^ 1])[ch1] = rb1;
      } else if (BMODE == 1) {
        const int kb = (kk + 1) * 32 + kp0;
        ((i4v*)sBr[cur ^ 1])[ch0] = applyPack8(rb0, scB, shB, kb);
        ((i4v*)sBr[cur ^ 1])[ch1] = applyPack8(rb1, scB, shB, kb);
      } else if (BMODE == 2) {
        const int kb = (kk + 1) * 32 + kp0;
        ((i4v*)sBr[cur ^ 1])[ch0] = selPack8b(rb0, rn0, scB, shB, kb);
        ((i4v*)sBr[cur ^ 1])[ch1] = selPack8b(rb1, rn1, scB, shB, kb);
      } else {
        float* sBfn = (float*)sBr[cur ^ 1];
#pragma unroll
        for (int it = 0; it < 4; ++it) {
          float* dst = sBfn + kS * XSTRIDE + nS + it * 32;
          ((float2*)dst)[0] = make_float2(xv[it][0], xv[it][1]);
          ((float2*)dst)[1] = make_float2(xv[it][2], xv[it][3]);
        }
      }
    }
    __syncthreads();
    cur ^= 1;
  }
  // epilogue: D col(n)=lane&15, row(o)=(lane>>4)*4+reg
  const int og = m0 + wr * 64 + (lane >> 4) * 4;
  const int ng = n0 + wc * 64 + r15;
  if (BF16OUT) {
    u16* Yp = (u16*)Yv + (long)b * strideY;
#pragma unroll
    for (int mi = 0; mi < 4; ++mi)
#pragma unroll
      for (int ni = 0; ni < 4; ++ni) {
        f4 a = acc[mi][ni];
        u16x4 r;
#pragma unroll
        for (int q = 0; q < 4; ++q) r[q] = f2b(a[q]);
        *(u16x4*)(Yp + (long)(ng + ni * 16) * M + og + mi * 16) = r;
      }
  } else {
    float* Yp = (float*)Yv + (long)b * strideY;
#pragma unroll
    for (int mi = 0; mi < 4; ++mi)
#pragma unroll
      for (int ni = 0; ni < 4; ++ni)
        *(f4*)(Yp + (long)(ng + ni * 16) * M + og + mi * 16) = acc[mi][ni];
  }
  if (STATS) {
#pragma unroll
    for (int mi = 0; mi < 4; ++mi)
#pragma unroll
      for (int j = 0; j < 4; ++j) {
        float s = 0.f, q = 0.f;
#pragma unroll
        for (int ni = 0; ni < 4; ++ni) {
          float v = acc[mi][ni][j];
          s += v; q = fmaf(v, v, q);
        }
#pragma unroll
        for (int off = 1; off < 16; off <<= 1) {
          s += __shfl_xor(s, off);
          q += __shfl_xor(q, off);
        }
        if ((lane & 15) == 0) {
          int lc = wr * 64 + (lane >> 4) * 4 + mi * 16 + j;
          atomicAdd(&s_sum[lc], s);
          atomicAdd(&s_ssq[lc], q);
        }
      }
    __syncthreads();
    if (tid < 128) {
      atomicAdd(&gsums[m0 + tid], s_sum[tid]);
      atomicAdd(&gssq[m0 + tid], s_ssq[tid]);
    }
  }
}

// ---------------- edgeconv gather, channel-split for L2 residency ----------------
__global__ __launch_bounds__(256, 2) void k_edge_gather(
    const u16* __restrict__ Y2, const int* __restrict__ idx,
    u16* __restrict__ Emax, u16* __restrict__ Emin,
    float* __restrict__ sums, float* __restrict__ ssq)
{
  __shared__ float s_sum[256], s_ssq[256];
  const int tid = threadIdx.x, lane = tid & 63, w = tid >> 6;
  s_sum[tid] = 0.f; s_ssq[tid] = 0.f;
  __syncthreads();
  const int half = blockIdx.y, b = blockIdx.z;
  const int ptBase = blockIdx.x * 64 + w * 16;
  const int sub = lane >> 5;
  const int chOff = half * 128 + ((lane & 31) << 2);
  f4 lsum = {0.f, 0.f, 0.f, 0.f}, lssq = {0.f, 0.f, 0.f, 0.f};
  for (int i = 0; i < 8; ++i) {
    const int pt = ptBase + i * 2 + sub;
    const long gp = (long)b * 8192 + pt;
    u16x4 cr = *(const u16x4*)(Y2 + gp * 512 + 256 + chOff);
    f4 ctr; ctr[0] = b2f(cr[0]); ctr[1] = b2f(cr[1]); ctr[2] = b2f(cr[2]); ctr[3] = b2f(cr[3]);
    const int* irow = idx + gp * 20;
    f4 vmax = {-3.0e38f, -3.0e38f, -3.0e38f, -3.0e38f};
    f4 vmin = {3.0e38f, 3.0e38f, 3.0e38f, 3.0e38f};
#pragma unroll 4
    for (int k = 0; k < 20; ++k) {
      int m = irow[k];
      u16x4 nr = *(const u16x4*)(Y2 + ((long)b * 8192 + m) * 512 + chOff);
#pragma unroll
      for (int j = 0; j < 4; ++j) {
        float y = b2f(nr[j]) + ctr[j];
        vmax[j] = fmaxf(vmax[j], y);
        vmin[j] = fminf(vmin[j], y);
        lsum[j] += y;
        lssq[j] = fmaf(y, y, lssq[j]);
      }
    }
    u16x4 eM, eN;
#pragma unroll
    for (int j = 0; j < 4; ++j) { eM[j] = f2b(vmax[j]); eN[j] = f2b(vmin[j]); }
    *(u16x4*)(Emax + gp * 256 + chOff) = eM;
    *(u16x4*)(Emin + gp * 256 + chOff) = eN;
  }
#pragma unroll
  for (int j = 0; j < 4; ++j) {
    atomicAdd(&s_sum[chOff + j], lsum[j]);
    atomicAdd(&s_ssq[chOff + j], lssq[j]);
  }
  __syncthreads();
  atomicAdd(&sums[tid], s_sum[tid]);
  atomicAdd(&ssq[tid], s_ssq[tid]);
}

// ---------------- final: apply(norm3+leaky) + 50x128 proj + bias; Y4 read ONCE ----------------
__global__ __launch_bounds__(64) void k_final(
    const float* __restrict__ Y4, const float* __restrict__ sums, const float* __restrict__ ssq,
    const float* __restrict__ g, const float* __restrict__ bt,
    const float* __restrict__ wf, const float* __restrict__ bf,
    float* __restrict__ out)
{
  __shared__ float swf[128][56];
  __shared__ float sc[128], sh[128], sb[52];
  const int lane = threadIdx.x;
  if (lane < 50) {
    const float* wrow = wf + lane * 128;
#pragma unroll 8
    for (int ch = 0; ch < 128; ++ch) swf[ch][lane] = wrow[ch];
    sb[lane] = bf[lane];
  } else if (lane < 52) {
#pragma unroll 8
    for (int ch = 0; ch < 128; ++ch) swf[ch][lane] = 0.f;
    sb[lane] = 0.f;
  }
#pragma unroll
  for (int t = 0; t < 2; ++t) {
    int ch = lane + t * 64;
    float m = sums[ch] * (1.0f / 16384.0f);
    float v = ssq[ch] * (1.0f / 16384.0f) - m * m;
    float s = g[ch] / sqrtf(v + 1e-5f);
    sc[ch] = s;
    sh[ch] = bt[ch] - m * s;
  }
  __syncthreads();
  const int b = blockIdx.y;
  const int n = blockIdx.x * 64 + lane;
  const float* hp = Y4 + ((long)b * 8192 + n) * 128;
  f4 av[13];
#pragma unroll
  for (int i = 0; i < 13; ++i) { f4 z = {0.f, 0.f, 0.f, 0.f}; av[i] = z; }
#pragma unroll 4
  for (int c4 = 0; c4 < 32; ++c4) {
    f4 hv = *(const f4*)(hp + c4 * 4);
#pragma unroll
    for (int e = 0; e < 4; ++e) {
      const int ch = c4 * 4 + e;
      float z = lky(fmaf(sc[ch], hv[e], sh[ch]));
#pragma unroll
      for (int o4 = 0; o4 < 13; ++o4) {
        f4 wv = *(const f4*)&swf[ch][o4 * 4];
#pragma unroll
        for (int q = 0; q < 4; ++q) av[o4][q] = fmaf(z, wv[q], av[o4][q]);
      }
    }
  }
  float* ob = out + (((long)b * 50) << 13) + n;
#pragma unroll
  for (int o4 = 0; o4 < 13; ++o4)
#pragma unroll
    for (int q = 0; q < 4; ++q) {
      int o = o4 * 4 + q;
      if (o < 50) ob[(long)o << 13] = av[o4][q] + sb[o];
    }
}

// ---------------- launcher ----------------
extern "C" void kernel_launch(void* const* d_in, const int* in_sizes, int n_in,
                              void* d_out, int out_size, void* d_ws, size_t ws_size,
                              hipStream_t stream)
{
  if ((long)ws_size < WS_NEED) return;
  const float* x   = (const float*)d_in[0];
  const float* p   = (const float*)d_in[1];
  const float* w1  = (const float*)d_in[2];
  const float* g1w = (const float*)d_in[4];
  const float* bt1 = (const float*)d_in[5];
  const float* we  = (const float*)d_in[6];
  const float* gew = (const float*)d_in[8];
  const float* bte = (const float*)d_in[9];
  const float* w2  = (const float*)d_in[10];
  const float* g2w = (const float*)d_in[12];
  const float* bt2 = (const float*)d_in[13];
  const float* w3  = (const float*)d_in[14];
  const float* g3w = (const float*)d_in[16];
  const float* bt3 = (const float*)d_in[17];
  const float* wf  = (const float*)d_in[18];
  const float* bfi = (const float*)d_in[19];

  char* ws = (char*)d_ws;
  u16* w1b   = (u16*)(ws + OFF_W1B);
  u16* weABb = (u16*)(ws + OFF_WEAB);
  u16* w2b   = (u16*)(ws + OFF_W2B);
  u16* w3b   = (u16*)(ws + OFF_W3B);
  int* idxb  = (int*)(ws + OFF_IDX);
  f4*  pqg   = (f4*)(ws + OFF_PQ);
  u16*   Y1b  = (u16*)(ws + OFF_Y1);
  u16*   Y2b  = (u16*)(ws + OFF_Y2);
  u16*   EMAX = (u16*)(ws + OFF_EMAX);
  u16*   EMIN = (u16*)(ws + OFF_EMIN);
  u16*   Y3b  = (u16*)(ws + OFF_Y3);
  float* Y4   = (float*)(ws + OFF_Y4);
  float* st0 = (float*)(ws + OFF_STATS);
  float* st1 = (float*)(ws + OFF_STATS + 4096);
  float* st2 = (float*)(ws + OFF_STATS + 8192);
  float* st3 = (float*)(ws + OFF_STATS + 12288);

  hipMemsetAsync(ws + OFF_STATS, 0, 16384, stream);
  k_convw<<<2176, 256, 0, stream>>>(w1, we, w2, w3, p, w1b, weABb, w2b, w3b, pqg);
  k_knn<<<1024, 256, 0, stream>>>(pqg, idxb);

  // stage 1: smlp1d(x, w1) -> Y1 bf16 raw + stats st0; B staged straight from x (fused transpose)
  k_gemm<3, 1, 1><<<dim3(64, 2, 2), 256, 0, stream>>>(
      w1b, x, nullptr, nullptr, nullptr, nullptr, nullptr, 0.f,
      st0, st0 + 256, Y1b, 256, 1216, (long)1216 * 8192, (long)8192 * 256);

  // edge GEMM: B = apply1(Y1 bf16) fused -> Y2 bf16 [Anb | Cy]
  k_gemm<1, 0, 1><<<dim3(64, 4, 2), 256, 0, stream>>>(
      weABb, Y1b, nullptr, st0, st0 + 256, g1w, bt1, 1.0f / 16384.0f,
      nullptr, nullptr, Y2b, 512, 256, (long)8192 * 256, (long)8192 * 512);

  // gather: channel-split, bf16 E out, stats st1
  k_edge_gather<<<dim3(128, 2, 2), 256, 0, stream>>>(Y2b, idxb, EMAX, EMIN, st1, st1 + 256);

  // stage 2: B = sel(EMAX,EMIN) bf16 fused -> Y3 bf16 raw + stats st2
  k_gemm<2, 1, 1><<<dim3(64, 2, 2), 256, 0, stream>>>(
      w2b, EMAX, EMIN, st1, st1 + 256, gew, bte, 1.0f / 327680.0f,
      st2, st2 + 256, Y3b, 256, 256, (long)8192 * 256, (long)8192 * 256);

  // stage 3: B = apply2(Y3 bf16) fused -> Y4 f32 + stats st3
  k_gemm<1, 1, 0><<<dim3(64, 1, 2), 256, 0, stream>>>(
      w3b, Y3b, nullptr, st2, st2 + 256, g2w, bt2, 1.0f / 16384.0f,
      st3, st3 + 256, Y4, 128, 256, (long)8192 * 256, (long)8192 * 128);

  // final: apply3 fused + projection (Y4 read once)
  k_final<<<dim3(128, 2), 64, 0, stream>>>(Y4, st3, st3 + 256, g3w, bt3, wf, bfi, (float*)d_out);
}